// Round 6
// baseline (301.139 us; speedup 1.0000x reference)
//
#include <hip/hip_runtime.h>

#define N_ITEMS 500000
#define EMBED 64
#define BATCH 1024
#define NCH ((N_ITEMS + 127) / 128)   // 3907 chunks of 128 items
#define CSTRIDE 256                   // chunk stride = gridDim.x
#define CAP 4096
#define MARGIN 0.75f                  // >> 2x max 1-term bf16 approx error

typedef __attribute__((ext_vector_type(8))) __bf16 bf16x8;
typedef __attribute__((ext_vector_type(4))) float f32x4;

__device__ unsigned g_cand[BATCH * CAP];   // 16 MB candidate lists

__device__ __forceinline__ void cvt_hi(const f32x4 r0, const f32x4 r1, bf16x8& H) {
#pragma unroll
  for (int k = 0; k < 4; ++k) { H[k] = (__bf16)r0[k]; H[4 + k] = (__bf16)r1[k]; }
}

__device__ __forceinline__ float u2f(unsigned tu) {
  union { unsigned u; float f; } cv;
  cv.u = (tu & 0x80000000u) ? (tu & 0x7FFFFFFFu) : ~tu;
  return cv.f;
}

__device__ __forceinline__ unsigned f2u(float f) {
  union { float f; int i; unsigned u; } cv; cv.f = f;
  return (cv.i < 0) ? ~cv.u : (cv.u | 0x80000000u);
}

// 3-way max; clang fuses fmaxf(fmaxf(a,b),c) -> v_max3_f32 on gfx9+
__device__ __forceinline__ float m3(float a, float b, float c) {
  return fmaxf(fmaxf(a, b), c);
}

// Fused seed+collect. Warm trips 0-1 (chunks bj, bj+256): max-only, SPECIALIZED
// loop body (no push code). After trip 0: fire-and-forget atomicMax publish.
// After trip 1: COHERENT fold via atomicMax(ptr, 0u) -- device-scope atomic
// read crosses XCD L2s (plain loads can serve stale per-XCD lines and miss
// other XCDs' publishes -> loose thresholds -> 7.7x push volume, round-5
// lesson). Freeze bs[] = max - MARGIN, Tm = min(bs). Hot trips 2..nc-1 +
// warm-chunk rescans nc..nc+1: round-0's fixed-threshold push body, also
// specialized. Threshold-at-push <= final threshold, so the MARGIN >= 2x
// bf16-error invariant holds for every push decision.
__global__ __launch_bounds__(512, 4)
void fused_scan(const float* __restrict__ emb, const int* __restrict__ idx,
                unsigned* __restrict__ best_u, unsigned* __restrict__ cnt) {
  __shared__ unsigned short Bb[2][128 * 64];   // 2 x 16 KB, granule-XOR swizzled
  __shared__ int sidx[512];

  const int tid = threadIdx.x, lane = tid & 63, wv = tid >> 6;
  const int l15 = lane & 15, kq = lane >> 4;
  const int bj = blockIdx.x, rh = blockIdx.y;
  const int m0 = wv * 64, rbase = rh * 512;

  {
    int row = idx[rbase + tid] - 1;
    if (row < 0) row += N_ITEMS;               // numpy negative-index wrap
    sidx[tid] = row;
  }
  const int sr = tid >> 2, sg = tid & 3;
  __syncthreads();

  bf16x8 ah[4][2];
#pragma unroll
  for (int am = 0; am < 4; ++am) {
    const float* src = emb + (size_t)sidx[m0 + am * 16 + l15] * EMBED + kq * 8;
    cvt_hi(*(const f32x4*)(src),      *(const f32x4*)(src + 4),  ah[am][0]);
    cvt_hi(*(const f32x4*)(src + 32), *(const f32x4*)(src + 36), ah[am][1]);
  }
  const int sw = sidx[m0 + lane];

  float bs[16];               // warm max; after the fold: fixed push threshold
  float Tm = 3.4e38f;
#pragma unroll
  for (int sl = 0; sl < 16; ++sl) bs[sl] = -3.4e38f;

  const int nc = (NCH - 1 - bj) / CSTRIDE + 1;   // 15 or 16 (nc >= 15 always)
  const int ntr = nc + 2;                        // + two warm-chunk rescans

  // prologue: load chunk bj (coalesced 64 B/thread)
  f32x4 raw[4];
  {
    int jr = bj * 128 + sr;
    if (jr >= N_ITEMS) jr = N_ITEMS - 1;
    const float* s = emb + (size_t)jr * EMBED + sg * 16;
#pragma unroll
    for (int i = 0; i < 4; ++i) raw[i] = *(const f32x4*)(s + 4 * i);
  }

  int p = 0;

  // ---- WARM loop: trips 0..1, max-only specialized body ----
  for (int it = 0; it < 2; ++it) {
    const int c = bj + it * CSTRIDE;
    {  // stage chunk c
      bf16x8 H0, H1;
      cvt_hi(raw[0], raw[1], H0);
      cvt_hi(raw[2], raw[3], H1);
      const int g0 = (2 * sg) ^ (sr & 7), g1 = (2 * sg + 1) ^ (sr & 7);
      *(bf16x8*)(Bb[p] + sr * 64 + g0 * 8) = H0;
      *(bf16x8*)(Bb[p] + sr * 64 + g1 * 8) = H1;
    }
    __syncthreads();
    {  // prefetch next trip's chunk (it+1 < nc always, since nc >= 15)
      int jr = (bj + (it + 1) * CSTRIDE) * 128 + sr;
      if (jr >= N_ITEMS) jr = N_ITEMS - 1;
      const float* s = emb + (size_t)jr * EMBED + sg * 16;
#pragma unroll
      for (int i = 0; i < 4; ++i) raw[i] = *(const f32x4*)(s + 4 * i);
    }

    const bool masked = __any((sw >> 7) == c);

#pragma unroll
    for (int bn = 0; bn < 8; ++bn) {
      const int row16 = bn * 16 + l15;
      const int fro = row16 * 64;
      bf16x8 bh0 = *(const bf16x8*)(Bb[p] + fro + ((kq ^ (row16 & 7)) << 3));
      bf16x8 bh1 = *(const bf16x8*)(Bb[p] + fro + (((4 | kq) ^ (row16 & 7)) << 3));
      const f32x4 zero = {0.f, 0.f, 0.f, 0.f};
      f32x4 acc[4];
#pragma unroll
      for (int am = 0; am < 4; ++am) {
        acc[am] = __builtin_amdgcn_mfma_f32_16x16x32_bf16(ah[am][0], bh0, zero, 0, 0, 0);
        acc[am] = __builtin_amdgcn_mfma_f32_16x16x32_bf16(ah[am][1], bh1, acc[am], 0, 0, 0);
      }
      if (!masked) {
#pragma unroll
        for (int sl = 0; sl < 16; ++sl)
          bs[sl] = fmaxf(bs[sl], acc[sl >> 2][sl & 3]);
      } else {   // rare: warm chunk holds a self row
        const int jc = c * 128 + bn * 16 + l15;
#pragma unroll
        for (int sl = 0; sl < 16; ++sl) {
          const int self = sidx[m0 + (sl >> 2) * 16 + kq * 4 + (sl & 3)];
          float v = (jc != self) ? acc[sl >> 2][sl & 3] : -3.4e38f;
          bs[sl] = fmaxf(bs[sl], v);
        }
      }
    }

    // reduce row maxima across the 16-lane group (butterfly -> all lanes)
#pragma unroll
    for (int off = 1; off < 16; off <<= 1)
#pragma unroll
      for (int sl = 0; sl < 16; ++sl)
        bs[sl] = fmaxf(bs[sl], __shfl_xor(bs[sl], off, 64));

    if (it == 0) {
      // fire-and-forget publish (return unused -> no wait)
      if (l15 == 0) {
#pragma unroll
        for (int sl = 0; sl < 16; ++sl)
          atomicMax(best_u + rbase + m0 + (sl >> 2) * 16 + kq * 4 + (sl & 3),
                    f2u(bs[sl]));
      }
    } else {
      // COHERENT fold: atomic read (atomicMax with 0 never stores; best_u
      // encodings are always > 0), leader lanes only, then broadcast
#pragma unroll
      for (int sl = 0; sl < 16; ++sl) {
        float v = bs[sl];
        if (l15 == 0) {
          unsigned g = atomicMax(
              best_u + rbase + m0 + (sl >> 2) * 16 + kq * 4 + (sl & 3), 0u);
          if (g) v = fmaxf(v, u2f(g));   // g==0 <=> unpublished
        }
        bs[sl] = __shfl(v, lane & 48, 64) - MARGIN;  // broadcast from leader
      }
      Tm = bs[0];
#pragma unroll
      for (int sl = 1; sl < 16; ++sl) Tm = fminf(Tm, bs[sl]);
    }
    p ^= 1;
  }

  // ---- HOT loop: trips 2..ntr-1, push-only specialized body ----
  for (int it = 2; it < ntr; ++it) {
    const int c = (it < nc) ? bj + it * CSTRIDE : bj + (it - nc) * CSTRIDE;
    {  // stage chunk c
      bf16x8 H0, H1;
      cvt_hi(raw[0], raw[1], H0);
      cvt_hi(raw[2], raw[3], H1);
      const int g0 = (2 * sg) ^ (sr & 7), g1 = (2 * sg + 1) ^ (sr & 7);
      *(bf16x8*)(Bb[p] + sr * 64 + g0 * 8) = H0;
      *(bf16x8*)(Bb[p] + sr * 64 + g1 * 8) = H1;
    }
    __syncthreads();
    {  // prefetch next trip's chunk
      const int nit = it + 1;
      if (nit < ntr) {
        const int cn = (nit < nc) ? bj + nit * CSTRIDE : bj + (nit - nc) * CSTRIDE;
        int jr = cn * 128 + sr;
        if (jr >= N_ITEMS) jr = N_ITEMS - 1;
        const float* s = emb + (size_t)jr * EMBED + sg * 16;
#pragma unroll
        for (int i = 0; i < 4; ++i) raw[i] = *(const f32x4*)(s + 4 * i);
      }
    }

#pragma unroll
    for (int bn = 0; bn < 8; ++bn) {
      const int row16 = bn * 16 + l15;
      const int fro = row16 * 64;
      bf16x8 bh0 = *(const bf16x8*)(Bb[p] + fro + ((kq ^ (row16 & 7)) << 3));
      bf16x8 bh1 = *(const bf16x8*)(Bb[p] + fro + (((4 | kq) ^ (row16 & 7)) << 3));
      const f32x4 zero = {0.f, 0.f, 0.f, 0.f};
      f32x4 acc[4];
#pragma unroll
      for (int am = 0; am < 4; ++am) {
        acc[am] = __builtin_amdgcn_mfma_f32_16x16x32_bf16(ah[am][0], bh0, zero, 0, 0, 0);
        acc[am] = __builtin_amdgcn_mfma_f32_16x16x32_bf16(ah[am][1], bh1, acc[am], 0, 0, 0);
      }
      // hot path: max3-tree of the 16 scores (8 ops, depth 3), one cmp vs Tm
      float t0 = m3(acc[0][0], acc[0][1], acc[0][2]);
      float t1 = m3(acc[0][3], acc[1][0], acc[1][1]);
      float t2 = m3(acc[1][2], acc[1][3], acc[2][0]);
      float t3 = m3(acc[2][1], acc[2][2], acc[2][3]);
      float t4 = m3(acc[3][0], acc[3][1], acc[3][2]);
      float gm = fmaxf(m3(t0, t1, t2), m3(t3, t4, acc[3][3]));
      if (__any(gm >= Tm)) {   // rare: per-slot push check (fixed thresholds)
        const int jc = c * 128 + bn * 16 + l15;
#pragma unroll
        for (int sl = 0; sl < 16; ++sl) {
          if (acc[sl >> 2][sl & 3] >= bs[sl] && jc < N_ITEMS) {
            const int gr = rbase + m0 + (sl >> 2) * 16 + kq * 4 + (sl & 3);
            unsigned pos = atomicAdd(cnt + gr, 1u);
            if (pos < CAP) g_cand[gr * CAP + pos] = (unsigned)jc;
          }
        }
      }
    }
    p ^= 1;
  }
}

// Exact fp32 rescore (one wave per row); inlines a full brute-force fallback
// for overflowed rows (expected candidates ~tens << CAP, so never taken).
__global__ __launch_bounds__(512)
void rescore_kernel(const float* __restrict__ emb, const int* __restrict__ idx,
                    const unsigned* __restrict__ cnt,
                    const float* __restrict__ mn, const float* __restrict__ mx,
                    float* __restrict__ out) {
  const int lane = threadIdx.x & 63, wv = threadIdx.x >> 6;
  const int row = blockIdx.x * 8 + wv;
  int self = idx[row] - 1;
  if (self < 0) self += N_ITEMS;
  const float* a = emb + (size_t)self * EMBED;
  float av[EMBED];
#pragma unroll
  for (int k = 0; k < EMBED; k += 4) *(f32x4*)(av + k) = *(const f32x4*)(a + k);

  const unsigned n = cnt[row];
  float bv = -3.4e38f;
  unsigned bj = 0xFFFFFFFFu;
  if (n > CAP) {
    // overflow (never expected): exact scan of all items by this wave
    for (unsigned j = lane; j < N_ITEMS; j += 64) {
      if ((int)j == self) continue;
      const float* b = emb + (size_t)j * EMBED;
      float d = 0.f;
#pragma unroll
      for (int k = 0; k < EMBED; ++k) d = fmaf(av[k], b[k], d);
      if (d > bv || (d == bv && j < bj)) { bv = d; bj = j; }
    }
  } else {
    for (unsigned i = lane; i < n; i += 64) {
      unsigned j = g_cand[row * CAP + i];
      if ((int)j == self) continue;
      const float* b = emb + (size_t)j * EMBED;
      float d = 0.f;
#pragma unroll
      for (int k = 0; k < EMBED; ++k) d = fmaf(av[k], b[k], d);
      if (d > bv || (d == bv && j < bj)) { bv = d; bj = j; }
    }
  }
#pragma unroll
  for (int off = 1; off < 64; off <<= 1) {
    float ov = __shfl_xor(bv, off, 64);
    unsigned oj = (unsigned)__shfl_xor((int)bj, off, 64);
    if (ov > bv || (ov == bv && oj < bj)) { bv = ov; bj = oj; }
  }
  if (lane == 0) {
    float lo = mn[0], hi = mx[0];
    out[row] = (float)(bj + 1);
    out[BATCH + row] = (bv - lo) / (hi - lo);
  }
}

extern "C" void kernel_launch(void* const* d_in, const int* in_sizes, int n_in,
                              void* d_out, int out_size, void* d_ws, size_t ws_size,
                              hipStream_t stream) {
  const float* emb = (const float*)d_in[0];
  const int* idx   = (const int*)d_in[1];
  const float* mn  = (const float*)d_in[2];
  const float* mx  = (const float*)d_in[3];
  unsigned* ws     = (unsigned*)d_ws;
  unsigned* best_u = ws;                   // [1024]
  unsigned* cnt    = ws + 1024;            // [1024]

  hipMemsetAsync(d_ws, 0, 2048 * 4, stream);

  fused_scan<<<dim3(CSTRIDE, 2), dim3(512), 0, stream>>>(emb, idx, best_u, cnt);
  rescore_kernel<<<dim3(BATCH / 8), dim3(512), 0, stream>>>(
      emb, idx, cnt, mn, mx, (float*)d_out);
}

// Round 8
// 274.414 us; speedup vs baseline: 1.0974x; 1.0974x over previous
//
#include <hip/hip_runtime.h>

#define N_ITEMS 500000
#define EMBED 64
#define BATCH 1024
#define NCH ((N_ITEMS + 127) / 128)   // 3907 chunks of 128 items
#define SEED_CH 512                   // seed region: items 0..65535
#define CAP 4096
#define MARGIN 0.75f                  // >> 2x max 1-term bf16 approx error

typedef __attribute__((ext_vector_type(8))) __bf16 bf16x8;
typedef __attribute__((ext_vector_type(4))) float f32x4;

__device__ unsigned g_cand[BATCH * CAP];   // 16 MB candidate lists

__device__ __forceinline__ void cvt_hi(const f32x4 r0, const f32x4 r1, bf16x8& H) {
#pragma unroll
  for (int k = 0; k < 4; ++k) { H[k] = (__bf16)r0[k]; H[4 + k] = (__bf16)r1[k]; }
}

__device__ __forceinline__ float u2f(unsigned tu) {
  union { unsigned u; float f; } cv;
  cv.u = (tu & 0x80000000u) ? (tu & 0x7FFFFFFFu) : ~tu;
  return cv.f;
}

// 3-way max; clang fuses fmaxf(fmaxf(a,b),c) -> v_max3_f32 on gfx9+
__device__ __forceinline__ float m3(float a, float b, float c) {
  return fmaxf(fmaxf(a, b), c);
}

// MODE 0 (seed): per-row running max over [0, climit) chunks -> atomicMax(best_u).
// MODE 1 (collect): FIXED per-slot thresholds T = seedmax - MARGIN (plain loads:
// the seed->collect KERNEL BOUNDARY guarantees atomic visibility -- intra-kernel
// pooling was tried 3 ways in rounds 4-6 and never delivered tight thresholds).
// Hot path: max3-tree + ONE compare per 1024-score tile; rare slow path pushes.
template <int MODE>
__global__ __launch_bounds__(512, 4)
void scan_kernel(const float* __restrict__ emb, const int* __restrict__ idx,
                 unsigned* __restrict__ best_u, unsigned* __restrict__ cnt,
                 int climit, int stride) {
  __shared__ unsigned short Bb[2][128 * 64];   // 2 x 16 KB, granule-XOR swizzled
  __shared__ int sidx[512];

  const int tid = threadIdx.x, lane = tid & 63, wv = tid >> 6;
  const int l15 = lane & 15, kq = lane >> 4;
  const int bj = blockIdx.x, rh = blockIdx.y;
  const int m0 = wv * 64, rbase = rh * 512;

  {
    int row = idx[rbase + tid] - 1;
    if (row < 0) row += N_ITEMS;               // numpy negative-index wrap
    sidx[tid] = row;
  }
  const int sr = tid >> 2, sg = tid & 3;
  __syncthreads();

  bf16x8 ah[4][2];
#pragma unroll
  for (int am = 0; am < 4; ++am) {
    const float* src = emb + (size_t)sidx[m0 + am * 16 + l15] * EMBED + kq * 8;
    cvt_hi(*(const f32x4*)(src),      *(const f32x4*)(src + 4),  ah[am][0]);
    cvt_hi(*(const f32x4*)(src + 32), *(const f32x4*)(src + 36), ah[am][1]);
  }
  const int sw = sidx[m0 + lane];

  float bs[16];       // MODE0: running max; MODE1: fixed per-slot threshold
  float Tm = 0.f;     // MODE1: min over the lane's 16 thresholds
#pragma unroll
  for (int am = 0; am < 4; ++am)
#pragma unroll
    for (int r = 0; r < 4; ++r) {
      const int sl = am * 4 + r;
      if (MODE == 0) {
        bs[sl] = -3.4e38f;
      } else {
        bs[sl] = u2f(best_u[rbase + m0 + am * 16 + kq * 4 + r]) - MARGIN;
      }
    }
  if (MODE == 1) {
    Tm = bs[0];
#pragma unroll
    for (int sl = 1; sl < 16; ++sl) Tm = fminf(Tm, bs[sl]);
  }

  // prologue: load this block's first chunk (coalesced 64 B/thread)
  f32x4 raw[4];
  {
    int jr = bj * 128 + sr;
    if (jr >= N_ITEMS) jr = N_ITEMS - 1;
    const float* s = emb + (size_t)jr * EMBED + sg * 16;
#pragma unroll
    for (int i = 0; i < 4; ++i) raw[i] = *(const f32x4*)(s + 4 * i);
  }

  int p = 0;
  for (int c = bj; c < climit; c += stride) {
    {  // stage chunk c
      bf16x8 H0, H1;
      cvt_hi(raw[0], raw[1], H0);
      cvt_hi(raw[2], raw[3], H1);
      const int g0 = (2 * sg) ^ (sr & 7), g1 = (2 * sg + 1) ^ (sr & 7);
      *(bf16x8*)(Bb[p] + sr * 64 + g0 * 8) = H0;
      *(bf16x8*)(Bb[p] + sr * 64 + g1 * 8) = H1;
    }
    __syncthreads();
    {  // prefetch chunk c+stride: whole compute phase to complete
      int nc = c + stride;
      if (nc < climit) {
        int jr = nc * 128 + sr;
        if (jr >= N_ITEMS) jr = N_ITEMS - 1;
        const float* s = emb + (size_t)jr * EMBED + sg * 16;
#pragma unroll
        for (int i = 0; i < 4; ++i) raw[i] = *(const f32x4*)(s + 4 * i);
      }
    }

    const bool masked = (MODE == 0) && __any((sw >> 7) == c);

#pragma unroll
    for (int bn = 0; bn < 8; ++bn) {
      const int row16 = bn * 16 + l15;
      const int fro = row16 * 64;
      bf16x8 bh0 = *(const bf16x8*)(Bb[p] + fro + ((kq ^ (row16 & 7)) << 3));
      bf16x8 bh1 = *(const bf16x8*)(Bb[p] + fro + (((4 | kq) ^ (row16 & 7)) << 3));
      const f32x4 zero = {0.f, 0.f, 0.f, 0.f};
      f32x4 acc[4];
#pragma unroll
      for (int am = 0; am < 4; ++am) {
        acc[am] = __builtin_amdgcn_mfma_f32_16x16x32_bf16(ah[am][0], bh0, zero, 0, 0, 0);
        acc[am] = __builtin_amdgcn_mfma_f32_16x16x32_bf16(ah[am][1], bh1, acc[am], 0, 0, 0);
      }

      if (MODE == 0) {
        if (!masked) {
#pragma unroll
          for (int sl = 0; sl < 16; ++sl)
            bs[sl] = fmaxf(bs[sl], acc[sl >> 2][sl & 3]);
        } else {   // rare: chunk holds a self row
          const int jc = c * 128 + bn * 16 + l15;
#pragma unroll
          for (int sl = 0; sl < 16; ++sl) {
            const int self = sidx[m0 + (sl >> 2) * 16 + kq * 4 + (sl & 3)];
            float v = (jc != self) ? acc[sl >> 2][sl & 3] : -3.4e38f;
            bs[sl] = fmaxf(bs[sl], v);
          }
        }
      } else {
        // hot path: max3-tree of the 16 scores (8 ops, depth 3), one cmp vs Tm
        float t0 = m3(acc[0][0], acc[0][1], acc[0][2]);
        float t1 = m3(acc[0][3], acc[1][0], acc[1][1]);
        float t2 = m3(acc[1][2], acc[1][3], acc[2][0]);
        float t3 = m3(acc[2][1], acc[2][2], acc[2][3]);
        float t4 = m3(acc[3][0], acc[3][1], acc[3][2]);
        float gm = fmaxf(m3(t0, t1, t2), m3(t3, t4, acc[3][3]));
        if (__any(gm >= Tm)) {   // rare (~3-5% of tiles): per-slot push check
          const int jc = c * 128 + bn * 16 + l15;
#pragma unroll
          for (int sl = 0; sl < 16; ++sl) {
            if (acc[sl >> 2][sl & 3] >= bs[sl] && jc < N_ITEMS) {
              const int gr = rbase + m0 + (sl >> 2) * 16 + kq * 4 + (sl & 3);
              unsigned pos = atomicAdd(cnt + gr, 1u);
              if (pos < CAP) g_cand[gr * CAP + pos] = (unsigned)jc;
            }
          }
        }
      }
    }
    p ^= 1;
  }

  if (MODE == 0) {   // publish per-row seed max (self excluded)
#pragma unroll
    for (int off = 1; off < 16; off <<= 1)
#pragma unroll
      for (int sl = 0; sl < 16; ++sl)
        bs[sl] = fmaxf(bs[sl], __shfl_xor(bs[sl], off, 64));
    if (l15 == 0) {
#pragma unroll
      for (int sl = 0; sl < 16; ++sl) {
        union { float f; int i; unsigned u; } cv; cv.f = bs[sl];
        unsigned mu = (cv.i < 0) ? ~cv.u : (cv.u | 0x80000000u);
        atomicMax(best_u + rbase + m0 + (sl >> 2) * 16 + kq * 4 + (sl & 3), mu);
      }
    }
  }
}

// Exact fp32 rescore (one wave per row); inlines a full brute-force fallback
// for overflowed rows (expected candidates ~tens << CAP, so never taken).
__global__ __launch_bounds__(512)
void rescore_kernel(const float* __restrict__ emb, const int* __restrict__ idx,
                    const unsigned* __restrict__ cnt,
                    const float* __restrict__ mn, const float* __restrict__ mx,
                    float* __restrict__ out) {
  const int lane = threadIdx.x & 63, wv = threadIdx.x >> 6;
  const int row = blockIdx.x * 8 + wv;
  int self = idx[row] - 1;
  if (self < 0) self += N_ITEMS;
  const float* a = emb + (size_t)self * EMBED;
  float av[EMBED];
#pragma unroll
  for (int k = 0; k < EMBED; k += 4) *(f32x4*)(av + k) = *(const f32x4*)(a + k);

  const unsigned n = cnt[row];
  float bv = -3.4e38f;
  unsigned bj = 0xFFFFFFFFu;
  if (n > CAP) {
    // overflow (never expected): exact scan of all items by this wave
    for (unsigned j = lane; j < N_ITEMS; j += 64) {
      if ((int)j == self) continue;
      const float* b = emb + (size_t)j * EMBED;
      float d = 0.f;
#pragma unroll
      for (int k = 0; k < EMBED; ++k) d = fmaf(av[k], b[k], d);
      if (d > bv || (d == bv && j < bj)) { bv = d; bj = j; }
    }
  } else {
    for (unsigned i = lane; i < n; i += 64) {
      unsigned j = g_cand[row * CAP + i];
      if ((int)j == self) continue;
      const float* b = emb + (size_t)j * EMBED;
      float d = 0.f;
#pragma unroll
      for (int k = 0; k < EMBED; ++k) d = fmaf(av[k], b[k], d);
      if (d > bv || (d == bv && j < bj)) { bv = d; bj = j; }
    }
  }
#pragma unroll
  for (int off = 1; off < 64; off <<= 1) {
    float ov = __shfl_xor(bv, off, 64);
    unsigned oj = (unsigned)__shfl_xor((int)bj, off, 64);
    if (ov > bv || (ov == bv && oj < bj)) { bv = ov; bj = oj; }
  }
  if (lane == 0) {
    float lo = mn[0], hi = mx[0];
    out[row] = (float)(bj + 1);
    out[BATCH + row] = (bv - lo) / (hi - lo);
  }
}

extern "C" void kernel_launch(void* const* d_in, const int* in_sizes, int n_in,
                              void* d_out, int out_size, void* d_ws, size_t ws_size,
                              hipStream_t stream) {
  const float* emb = (const float*)d_in[0];
  const int* idx   = (const int*)d_in[1];
  const float* mn  = (const float*)d_in[2];
  const float* mx  = (const float*)d_in[3];
  unsigned* ws     = (unsigned*)d_ws;
  unsigned* best_u = ws;                   // [1024]
  unsigned* cnt    = ws + 1024;            // [1024]

  hipMemsetAsync(d_ws, 0, 2048 * 4, stream);

  // seed: per-row approx max over items 0..65535.
  // grid (256,2) = 512 blocks (2/CU, same co-residency as collect), 2 trips/block
  scan_kernel<0><<<dim3(256, 2), dim3(512), 0, stream>>>(emb, idx, best_u, cnt,
                                                         SEED_CH, 256);
  // collect: full scan, fixed thresholds (kernel boundary = visibility barrier)
  scan_kernel<1><<<dim3(256, 2), dim3(512), 0, stream>>>(emb, idx, best_u, cnt,
                                                         NCH, 256);
  // rescore with inlined exact fallback (replaces the two cleanup dispatches)
  rescore_kernel<<<dim3(BATCH / 8), dim3(512), 0, stream>>>(
      emb, idx, cnt, mn, mx, (float*)d_out);
}